// Round 2
// baseline (360.788 us; speedup 1.0000x reference)
//
#include <hip/hip_runtime.h>

// AttentionLayer, MFMA bf16 version.
// x (192,1024,128) f32; W_qkv (128,384) f32; W_out (128,128) f32; b_out (128) f32.
// out (192,1024,128) f32. H=8 heads x hd=16, N=SEQ=1024.
#define NBATCH 192
#define SEQ    1024
#define DIM    128
#define NH     8
#define EPS    1e-12f

typedef short bf16x8 __attribute__((ext_vector_type(8)));
typedef float f32x4  __attribute__((ext_vector_type(4)));

// ws layout: kvs 393216 f32, kssum 24576 f32, then bf16 wsWT frag-major [4][2048 frags][8]
#define KVS_F  393216
#define ZERO_F 417792

static __device__ __forceinline__ unsigned short f2bf(float f) {
    unsigned u = __builtin_bit_cast(unsigned, f);
    u += 0x7fff + ((u >> 16) & 1);          // RTNE
    return (unsigned short)(u >> 16);
}

template <int CTRL>
static __device__ __forceinline__ float dpp_add(float v) {
    int j = __builtin_amdgcn_mov_dpp(__builtin_bit_cast(int, v), CTRL, 0xf, 0xf, false);
    return v + __builtin_bit_cast(float, j);
}
// sum over the 16 lanes of a DPP row (= over n15); all lanes get the result
static __device__ __forceinline__ float r16sum(float v) {
    v = dpp_add<0xB1>(v);    // quad_perm [1,0,3,2]  : xor1
    v = dpp_add<0x4E>(v);    // quad_perm [2,3,0,1]  : xor2
    v = dpp_add<0x141>(v);   // row_half_mirror      : pairs 4-groups
    v = dpp_add<0x140>(v);   // row_mirror           : pairs 8-groups
    return v;
}

// strip: [row][32 els], granule(8 el)-swizzled by row&3. addr in shorts.
static __device__ __forceinline__ int strip_addr(int row, int el) {
    return row * 32 + ((((el >> 3) ^ (row & 3)) << 3) | (el & 7));
}

static __device__ __forceinline__ uint2 pack4(float a, float b, float c, float d) {
    uint2 r;
    r.x = (unsigned)f2bf(a) | ((unsigned)f2bf(b) << 16);
    r.y = (unsigned)f2bf(c) | ((unsigned)f2bf(d) << 16);
    return r;
}

static __device__ __forceinline__ bf16x8 cvt8(float4 a, float4 b) {
    bf16x8 r;
    r[0] = (short)f2bf(a.x); r[1] = (short)f2bf(a.y); r[2] = (short)f2bf(a.z); r[3] = (short)f2bf(a.w);
    r[4] = (short)f2bf(b.x); r[5] = (short)f2bf(b.y); r[6] = (short)f2bf(b.z); r[7] = (short)f2bf(b.w);
    return r;
}

// B-frag direct from global, frag-major wsWT: frag id = ((ct*4+ks)*4+q)*16+n15,
// 8 consecutive shorts per lane -> wave reads 1 KB contiguous (L1/L2 resident).
static __device__ __forceinline__ bf16x8 gfrag(const unsigned short* __restrict__ wT,
                                               int ct, int ks, int lane) {
    return *reinterpret_cast<const bf16x8*>(wT + ((ct * 4 + ks) * 64 + lane) * 8);
}

// ---------------- k0: convert weights into frag-major bf16 ----------------
// wsWT[which][(((ct*4+ks)*4+q)*16+n15)*8 + j] = W[k=ks*32+q*8+j][n=ct*16+n15]
__global__ __launch_bounds__(256) void k0_prep(const float* __restrict__ Wqkv,
                                               const float* __restrict__ Wout,
                                               unsigned short* __restrict__ wsWT) {
    int i = blockIdx.x * 256 + threadIdx.x;     // 0..65535, writes coalesced
    int which = i >> 14, e = i & 16383;
    int j = e & 7, f = e >> 3;
    int n15 = f & 15, q = (f >> 4) & 3, ks = (f >> 6) & 3, ct = f >> 8;
    int k = ks * 32 + q * 8 + j, n = ct * 16 + n15;
    float v = (which < 3) ? Wqkv[k * 384 + which * 128 + n] : Wout[k * 128 + n];
    wsWT[i] = f2bf(v);
}

// ---------------- k1: k,v GEMM -> normalize k -> kvs & ks_sum ----------------
// LDS 64 KB (2 blocks/CU): per-wave strips overlay the front of the reduction buffer.
// No weight staging, no barrier until the block-level kvs reduction.
__global__ __launch_bounds__(512, 4) void k1_kv(const float* __restrict__ x,
                                                const unsigned short* __restrict__ wsWT,
                                                float* __restrict__ kvs_ws,
                                                float* __restrict__ kssum_ws) {
    __shared__ float redf[16384];               // 64 KB
    unsigned short* strips = reinterpret_cast<unsigned short*>(redf);
    int t = threadIdx.x, w = t >> 6, lane = t & 63, q = lane >> 4, n15 = lane & 15;
    int b = blockIdx.x >> 2, seg = blockIdx.x & 3;
    const unsigned short* wkT = wsWT + 16384;   // W_k frags
    const unsigned short* wvT = wsWT + 32768;   // W_v frags
    unsigned short* knS = strips + w * 1024;    // [16 m][32 l]
    unsigned short* vS  = knS + 512;            // [16 d][32 l]

    bf16x8 ah[2][4];
#pragma unroll
    for (int rs = 0; rs < 2; ++rs) {
        int row = seg * 256 + w * 32 + rs * 16 + n15;
        const float* xr = x + (size_t)(b * SEQ + row) * DIM;
#pragma unroll
        for (int ks = 0; ks < 4; ++ks) {
            float4 p0 = *reinterpret_cast<const float4*>(xr + ks * 32 + q * 8);
            float4 p1 = *reinterpret_cast<const float4*>(xr + ks * 32 + q * 8 + 4);
            ah[rs][ks] = cvt8(p0, p1);
        }
    }

    f32x4 kvsacc[8];
    float ksum[8];
#pragma unroll
    for (int h = 0; h < 8; ++h) { kvsacc[h] = (f32x4){0,0,0,0}; ksum[h] = 0.f; }

#pragma unroll
    for (int ct = 0; ct < 8; ++ct) {
        f32x4 ka[2] = {(f32x4){0,0,0,0}, (f32x4){0,0,0,0}};
        f32x4 va[2] = {(f32x4){0,0,0,0}, (f32x4){0,0,0,0}};
#pragma unroll
        for (int ks = 0; ks < 4; ++ks) {
            bf16x8 kb = gfrag(wkT, ct, ks, lane);
            bf16x8 vb = gfrag(wvT, ct, ks, lane);
#pragma unroll
            for (int rs = 0; rs < 2; ++rs) {
                ka[rs] = __builtin_amdgcn_mfma_f32_16x16x32_bf16(ah[rs][ks], kb, ka[rs], 0, 0, 0);
                va[rs] = __builtin_amdgcn_mfma_f32_16x16x32_bf16(ah[rs][ks], vb, va[rs], 0, 0, 0);
            }
        }
        // normalize k rows (reduce over n15 = head dim), stash kn & v into strips
#pragma unroll
        for (int rs = 0; rs < 2; ++rs) {
            float kn[4];
#pragma unroll
            for (int r = 0; r < 4; ++r) {
                float val = ka[rs][r];
                float ssq = r16sum(val * val);
                float di  = 1.0f / fmaxf(sqrtf(ssq), EPS);
                kn[r] = val * di;
                ksum[ct] += kn[r];
            }
            *reinterpret_cast<uint2*>(knS + strip_addr(n15, rs * 16 + q * 4)) =
                pack4(kn[0], kn[1], kn[2], kn[3]);
            *reinterpret_cast<uint2*>(vS + strip_addr(n15, rs * 16 + q * 4)) =
                pack4(va[rs][0], va[rs][1], va[rs][2], va[rs][3]);
        }
        // kvs[h][m][d] += kn^T (m x l=32) . v (l x d)  — one K=32 MFMA
        bf16x8 aK = *reinterpret_cast<const bf16x8*>(knS + strip_addr(n15, q * 8));
        bf16x8 bV = *reinterpret_cast<const bf16x8*>(vS + strip_addr(n15, q * 8));
        kvsacc[ct] = __builtin_amdgcn_mfma_f32_16x16x32_bf16(aK, bV, kvsacc[ct], 0, 0, 0);
    }

    // ks_sum: reduce over q-groups (rows), then atomics from lanes 0..15
#pragma unroll
    for (int ct = 0; ct < 8; ++ct) {
        float s = ksum[ct];
        s += __shfl_xor(s, 16); s += __shfl_xor(s, 32);
        if (lane < 16) atomicAdd(&kssum_ws[b * 128 + ct * 16 + n15], s);
    }

    // block-level kvs reduction over 8 waves (reuses strip LDS), then one atomic per element
    __syncthreads();
#pragma unroll
    for (int ct = 0; ct < 8; ++ct)
#pragma unroll
        for (int r = 0; r < 4; ++r)
            redf[w * 2048 + ct * 256 + (q * 4 + r) * 16 + n15] = kvsacc[ct][r];
    __syncthreads();
#pragma unroll
    for (int i = 0; i < 4; ++i) {
        int el = i * 512 + t;
        float s = 0.f;
#pragma unroll
        for (int ww = 0; ww < 8; ++ww) s += redf[ww * 2048 + el];
        atomicAdd(&kvs_ws[b * 2048 + el], s);
    }
}

// ---------------- k2: per-rs {V GEMM -> Q GEMM -> fold+num MFMA} -> out proj ----------------
// LDS 80 KB (2 blocks/CU): kvsT 8K | strips 8K | per-wave tile 64K. ONE __syncthreads (kvsT).
// Register budget: per-rs split keeps peak ~115 VGPRs -> fits (512,4)'s 128 cap, no spill.
// Math (round-0 chaining): vacc = x@Wv; fold: vacc *= N*inv; pre = (qs*inv)@kvs + vacc  [MFMA C-op].
__global__ __launch_bounds__(512, 4) void k2_out(const float* __restrict__ x,
                                                 const unsigned short* __restrict__ wsWT,
                                                 const float* __restrict__ kvs_ws,
                                                 const float* __restrict__ kssum_ws,
                                                 const float* __restrict__ bout,
                                                 float* __restrict__ out) {
    __shared__ unsigned short lds[40960];       // 80 KB
    unsigned short* kvsT   = lds;               // [h*16+d][32 mpad] strip layout (8 KB)
    unsigned short* strips = lds + 4096;        // 8 waves x 512 shorts (8 KB)
    unsigned short* tile   = lds + 8192;        // 8 waves x (32 rows x 128 c) bf16 (64 KB)
    int t = threadIdx.x, w = t >> 6, lane = t & 63, q = lane >> 4, n15 = lane & 15;
    int b = blockIdx.x >> 2, seg = blockIdx.x & 3, rowbase = seg * 256;
    const unsigned short* wqT = wsWT;           // W_q frags
    const unsigned short* wvT = wsWT + 32768;   // W_v frags
    const unsigned short* woT = wsWT + 49152;   // W_out frags

    {   // build kvsT (bf16, transposed [h][d][m], m>=16 zero-padded)
        int row = t >> 2, part = t & 3, h = row >> 4, d = row & 15;
        unsigned es[8];
#pragma unroll
        for (int j = 0; j < 8; j += 2) {
            int m0 = part * 8 + j;
            unsigned lo = (m0     < 16) ? f2bf(kvs_ws[b * 2048 + h * 256 + m0 * 16 + d])      : 0;
            unsigned hi = (m0 + 1 < 16) ? f2bf(kvs_ws[b * 2048 + h * 256 + (m0 + 1) * 16 + d]) : 0;
            es[j] = lo | (hi << 16);
        }
        uint4 v = {es[0], es[2], es[4], es[6]};
        *reinterpret_cast<uint4*>(kvsT + row * 32 + ((part ^ (row & 3)) << 3)) = v;
    }

    float kss[8];
#pragma unroll
    for (int h = 0; h < 8; ++h) kss[h] = kssum_ws[b * 128 + h * 16 + n15];

    bf16x8 ah[2][4];
#pragma unroll
    for (int rs = 0; rs < 2; ++rs) {
        int row = rowbase + w * 32 + rs * 16 + n15;
        const float* xr = x + (size_t)(b * SEQ + row) * DIM;
#pragma unroll
        for (int ks = 0; ks < 4; ++ks) {
            float4 p0 = *reinterpret_cast<const float4*>(xr + ks * 32 + q * 8);
            float4 p1 = *reinterpret_cast<const float4*>(xr + ks * 32 + q * 8 + 4);
            ah[rs][ks] = cvt8(p0, p1);
        }
    }

    unsigned short* myS = strips + w * 512;     // per-wave 16x32 transpose strip
    unsigned short* tw  = tile + w * 4096;      // per-wave tile (32 rows x 128 c)
    {   // zero qs-strip pad (els 16..31 of each of 16 rows) — K=32 MFMA zero padding
        uint2 z = {0, 0};
        *reinterpret_cast<uint2*>(myS + strip_addr(n15, 16 + q * 4)) = z;
    }
    __syncthreads();                            // kvsT ready

#pragma unroll
    for (int rs = 0; rs < 2; ++rs) {
        // ---- V GEMM ----
        f32x4 vacc[8];
#pragma unroll
        for (int h = 0; h < 8; ++h) vacc[h] = (f32x4){0,0,0,0};
#pragma unroll
        for (int ct = 0; ct < 8; ++ct)
#pragma unroll
            for (int ks = 0; ks < 4; ++ks) {
                bf16x8 bb = gfrag(wvT, ct, ks, lane);
                vacc[ct] = __builtin_amdgcn_mfma_f32_16x16x32_bf16(ah[rs][ks], bb, vacc[ct], 0, 0, 0);
            }
        // ---- Q GEMM ----
        f32x4 qacc[8];
#pragma unroll
        for (int h = 0; h < 8; ++h) qacc[h] = (f32x4){0,0,0,0};
#pragma unroll
        for (int ct = 0; ct < 8; ++ct)
#pragma unroll
            for (int ks = 0; ks < 4; ++ks) {
                bf16x8 bb = gfrag(wqT, ct, ks, lane);
                qacc[ct] = __builtin_amdgcn_mfma_f32_16x16x32_bf16(ah[rs][ks], bb, qacc[ct], 0, 0, 0);
            }
        // ---- fold norms, numerator MFMA (C-op chain), write pre tile (wave-private) ----
#pragma unroll
        for (int h = 0; h < 8; ++h) {
            float pv[4];
#pragma unroll
            for (int r = 0; r < 4; ++r) {
                float val = qacc[h][r];
                float ssq = r16sum(val * val);
                float tt  = r16sum(val * kss[h]);
                float di  = 1.0f / fmaxf(sqrtf(ssq), EPS);
                float inv = 1.0f / (tt * di + (float)SEQ);
                pv[r] = val * di * inv;                 // qs * inv
                vacc[h][r] *= (float)SEQ * inv;         // N * v * inv
            }
#pragma unroll
            for (int r = 0; r < 4; ++r)
                myS[strip_addr(q * 4 + r, n15)] = f2bf(pv[r]);
            bf16x8 aq = *reinterpret_cast<const bf16x8*>(myS + strip_addr(n15, q * 8));
            bf16x8 bk = *reinterpret_cast<const bf16x8*>(kvsT + strip_addr(h * 16 + n15, q * 8));
            vacc[h] = __builtin_amdgcn_mfma_f32_16x16x32_bf16(aq, bk, vacc[h], 0, 0, 0); // = pre
#pragma unroll
            for (int r = 0; r < 4; ++r) {
                int rt = rs * 16 + q * 4 + r;
                int colg = h * 2 + (n15 >> 3);
                tw[rt * 128 + (((colg ^ (rt & 15)) << 3) | (n15 & 7))] = f2bf(vacc[h][r]);
            }
        }
    }

    // ---- out projection (tile is wave-private: no barrier) ----
    bf16x8 ap[2][4];
#pragma unroll
    for (int rs = 0; rs < 2; ++rs)
#pragma unroll
        for (int ks = 0; ks < 4; ++ks) {
            int rt = rs * 16 + n15;
            ap[rs][ks] = *reinterpret_cast<const bf16x8*>(
                tw + rt * 128 + ((((ks << 2) + q) ^ (rt & 15)) << 3));
        }
    f32x4 oacc[2][8];
#pragma unroll
    for (int rs = 0; rs < 2; ++rs)
#pragma unroll
        for (int h = 0; h < 8; ++h) oacc[rs][h] = (f32x4){0,0,0,0};
#pragma unroll
    for (int ct = 0; ct < 8; ++ct)
#pragma unroll
        for (int ks = 0; ks < 4; ++ks) {
            bf16x8 bb = gfrag(woT, ct, ks, lane);
#pragma unroll
            for (int rs = 0; rs < 2; ++rs)
                oacc[rs][ct] = __builtin_amdgcn_mfma_f32_16x16x32_bf16(ap[rs][ks], bb, oacc[rs][ct], 0, 0, 0);
        }
#pragma unroll
    for (int ct = 0; ct < 8; ++ct) {
        float bo = bout[ct * 16 + n15];
#pragma unroll
        for (int rs = 0; rs < 2; ++rs)
#pragma unroll
            for (int r = 0; r < 4; ++r) {
                int row = rowbase + w * 32 + rs * 16 + q * 4 + r;
                out[(size_t)(b * SEQ + row) * DIM + ct * 16 + n15] = oacc[rs][ct][r] + bo;
            }
    }
}

extern "C" void kernel_launch(void* const* d_in, const int* in_sizes, int n_in,
                              void* d_out, int out_size, void* d_ws, size_t ws_size,
                              hipStream_t stream) {
    const float* x    = (const float*)d_in[0];
    const float* Wqkv = (const float*)d_in[1];
    const float* Wout = (const float*)d_in[2];
    const float* bout = (const float*)d_in[3];
    float* out = (float*)d_out;

    float* kvs_ws   = (float*)d_ws;
    float* kssum_ws = kvs_ws + KVS_F;
    unsigned short* wsWT = (unsigned short*)((char*)d_ws + (size_t)ZERO_F * 4);

    hipMemsetAsync(d_ws, 0, (size_t)ZERO_F * 4, stream);   // zero kvs + kssum (graph-capturable)
    k0_prep<<<dim3(256), dim3(256), 0, stream>>>(Wqkv, Wout, wsWT);
    k1_kv<<<dim3(768), dim3(512), 0, stream>>>(x, wsWT, kvs_ws, kssum_ws);
    k2_out<<<dim3(768), dim3(512), 0, stream>>>(x, wsWT, kvs_ws, kssum_ws, bout, out);
}

// Round 3
// 316.930 us; speedup vs baseline: 1.1384x; 1.1384x over previous
//
#include <hip/hip_runtime.h>

// AttentionLayer, MFMA bf16 version.
// x (192,1024,128) f32; W_qkv (128,384) f32; W_out (128,128) f32; b_out (128) f32.
// out (192,1024,128) f32. H=8 heads x hd=16, N=SEQ=1024.
#define NBATCH 192
#define SEQ    1024
#define DIM    128
#define NH     8
#define EPS    1e-12f

typedef short bf16x8 __attribute__((ext_vector_type(8)));
typedef float f32x4  __attribute__((ext_vector_type(4)));

// ws layout: kvs 393216 f32, kssum 24576 f32, then bf16 wsWT frag-major [4][2048 frags][8]
#define KVS_F  393216
#define ZERO_F 417792

static __device__ __forceinline__ unsigned short f2bf(float f) {
    unsigned u = __builtin_bit_cast(unsigned, f);
    u += 0x7fff + ((u >> 16) & 1);          // RTNE
    return (unsigned short)(u >> 16);
}

template <int CTRL>
static __device__ __forceinline__ float dpp_add(float v) {
    int j = __builtin_amdgcn_mov_dpp(__builtin_bit_cast(int, v), CTRL, 0xf, 0xf, false);
    return v + __builtin_bit_cast(float, j);
}
// sum over the 16 lanes of a DPP row (= over n15); all lanes get the result
static __device__ __forceinline__ float r16sum(float v) {
    v = dpp_add<0xB1>(v);    // quad_perm [1,0,3,2]  : xor1
    v = dpp_add<0x4E>(v);    // quad_perm [2,3,0,1]  : xor2
    v = dpp_add<0x141>(v);   // row_half_mirror      : pairs 4-groups
    v = dpp_add<0x140>(v);   // row_mirror           : pairs 8-groups
    return v;
}

// strip: [row][32 els], granule(8 el)-swizzled by row&3. addr in shorts.
static __device__ __forceinline__ int strip_addr(int row, int el) {
    return row * 32 + ((((el >> 3) ^ (row & 3)) << 3) | (el & 7));
}

static __device__ __forceinline__ uint2 pack4(float a, float b, float c, float d) {
    uint2 r;
    r.x = (unsigned)f2bf(a) | ((unsigned)f2bf(b) << 16);
    r.y = (unsigned)f2bf(c) | ((unsigned)f2bf(d) << 16);
    return r;
}

static __device__ __forceinline__ bf16x8 cvt8(float4 a, float4 b) {
    bf16x8 r;
    r[0] = (short)f2bf(a.x); r[1] = (short)f2bf(a.y); r[2] = (short)f2bf(a.z); r[3] = (short)f2bf(a.w);
    r[4] = (short)f2bf(b.x); r[5] = (short)f2bf(b.y); r[6] = (short)f2bf(b.z); r[7] = (short)f2bf(b.w);
    return r;
}

// B-frag direct from global, frag-major wsWT: frag id = ((ct*4+ks)*4+q)*16+n15,
// 8 consecutive shorts per lane -> wave reads 1 KB contiguous (L1/L2 resident).
static __device__ __forceinline__ bf16x8 gfrag(const unsigned short* __restrict__ wT,
                                               int ct, int ks, int lane) {
    return *reinterpret_cast<const bf16x8*>(wT + ((ct * 4 + ks) * 64 + lane) * 8);
}

// ---------------- k0: convert weights into frag-major bf16 ----------------
// wsWT[which][(((ct*4+ks)*4+q)*16+n15)*8 + j] = W[k=ks*32+q*8+j][n=ct*16+n15]
__global__ __launch_bounds__(256) void k0_prep(const float* __restrict__ Wqkv,
                                               const float* __restrict__ Wout,
                                               unsigned short* __restrict__ wsWT) {
    int i = blockIdx.x * 256 + threadIdx.x;     // 0..65535, writes coalesced
    int which = i >> 14, e = i & 16383;
    int j = e & 7, f = e >> 3;
    int n15 = f & 15, q = (f >> 4) & 3, ks = (f >> 6) & 3, ct = f >> 8;
    int k = ks * 32 + q * 8 + j, n = ct * 16 + n15;
    float v = (which < 3) ? Wqkv[k * 384 + which * 128 + n] : Wout[k * 128 + n];
    wsWT[i] = f2bf(v);
}

// ---------------- k1: k,v GEMM -> normalize k -> kvs & ks_sum ----------------
// LDS 64 KB (2 blocks/CU): per-wave strips overlay the front of the reduction buffer.
// No weight staging, no barrier until the block-level kvs reduction.
__global__ __launch_bounds__(512, 4) void k1_kv(const float* __restrict__ x,
                                                const unsigned short* __restrict__ wsWT,
                                                float* __restrict__ kvs_ws,
                                                float* __restrict__ kssum_ws) {
    __shared__ float redf[16384];               // 64 KB
    unsigned short* strips = reinterpret_cast<unsigned short*>(redf);
    int t = threadIdx.x, w = t >> 6, lane = t & 63, q = lane >> 4, n15 = lane & 15;
    int b = blockIdx.x >> 2, seg = blockIdx.x & 3;
    const unsigned short* wkT = wsWT + 16384;   // W_k frags
    const unsigned short* wvT = wsWT + 32768;   // W_v frags
    unsigned short* knS = strips + w * 1024;    // [16 m][32 l]
    unsigned short* vS  = knS + 512;            // [16 d][32 l]

    bf16x8 ah[2][4];
#pragma unroll
    for (int rs = 0; rs < 2; ++rs) {
        int row = seg * 256 + w * 32 + rs * 16 + n15;
        const float* xr = x + (size_t)(b * SEQ + row) * DIM;
#pragma unroll
        for (int ks = 0; ks < 4; ++ks) {
            float4 p0 = *reinterpret_cast<const float4*>(xr + ks * 32 + q * 8);
            float4 p1 = *reinterpret_cast<const float4*>(xr + ks * 32 + q * 8 + 4);
            ah[rs][ks] = cvt8(p0, p1);
        }
    }

    f32x4 kvsacc[8];
    float ksum[8];
#pragma unroll
    for (int h = 0; h < 8; ++h) { kvsacc[h] = (f32x4){0,0,0,0}; ksum[h] = 0.f; }

#pragma unroll
    for (int ct = 0; ct < 8; ++ct) {
        f32x4 ka[2] = {(f32x4){0,0,0,0}, (f32x4){0,0,0,0}};
        f32x4 va[2] = {(f32x4){0,0,0,0}, (f32x4){0,0,0,0}};
#pragma unroll
        for (int ks = 0; ks < 4; ++ks) {
            bf16x8 kb = gfrag(wkT, ct, ks, lane);
            bf16x8 vb = gfrag(wvT, ct, ks, lane);
#pragma unroll
            for (int rs = 0; rs < 2; ++rs) {
                ka[rs] = __builtin_amdgcn_mfma_f32_16x16x32_bf16(ah[rs][ks], kb, ka[rs], 0, 0, 0);
                va[rs] = __builtin_amdgcn_mfma_f32_16x16x32_bf16(ah[rs][ks], vb, va[rs], 0, 0, 0);
            }
        }
        // normalize k rows (reduce over n15 = head dim), stash kn & v into strips
#pragma unroll
        for (int rs = 0; rs < 2; ++rs) {
            float kn[4];
#pragma unroll
            for (int r = 0; r < 4; ++r) {
                float val = ka[rs][r];
                float ssq = r16sum(val * val);
                float di  = 1.0f / fmaxf(sqrtf(ssq), EPS);
                kn[r] = val * di;
                ksum[ct] += kn[r];
            }
            *reinterpret_cast<uint2*>(knS + strip_addr(n15, rs * 16 + q * 4)) =
                pack4(kn[0], kn[1], kn[2], kn[3]);
            *reinterpret_cast<uint2*>(vS + strip_addr(n15, rs * 16 + q * 4)) =
                pack4(va[rs][0], va[rs][1], va[rs][2], va[rs][3]);
        }
        // kvs[h][m][d] += kn^T (m x l=32) . v (l x d)  — one K=32 MFMA
        bf16x8 aK = *reinterpret_cast<const bf16x8*>(knS + strip_addr(n15, q * 8));
        bf16x8 bV = *reinterpret_cast<const bf16x8*>(vS + strip_addr(n15, q * 8));
        kvsacc[ct] = __builtin_amdgcn_mfma_f32_16x16x32_bf16(aK, bV, kvsacc[ct], 0, 0, 0);
    }

    // ks_sum: reduce over q-groups (rows), then atomics from lanes 0..15
#pragma unroll
    for (int ct = 0; ct < 8; ++ct) {
        float s = ksum[ct];
        s += __shfl_xor(s, 16); s += __shfl_xor(s, 32);
        if (lane < 16) atomicAdd(&kssum_ws[b * 128 + ct * 16 + n15], s);
    }

    // block-level kvs reduction over 8 waves (reuses strip LDS), then one atomic per element
    __syncthreads();
#pragma unroll
    for (int ct = 0; ct < 8; ++ct)
#pragma unroll
        for (int r = 0; r < 4; ++r)
            redf[w * 2048 + ct * 256 + (q * 4 + r) * 16 + n15] = kvsacc[ct][r];
    __syncthreads();
#pragma unroll
    for (int i = 0; i < 4; ++i) {
        int el = i * 512 + t;
        float s = 0.f;
#pragma unroll
        for (int ww = 0; ww < 8; ++ww) s += redf[ww * 2048 + el];
        atomicAdd(&kvs_ws[b * 2048 + el], s);
    }
}

// ---------------- k2: per-(rs,h) {Q,V head-GEMM -> fold -> num MFMA -> tile} -> out proj ----------------
// LDS 80 KB (2 blocks/CU): kvsT 8K | strips 8K | per-wave tile 64K. ONE __syncthreads (kvsT).
// Register plan: per-head accumulators (qa,va = 8 regs) retire into the wave-private tile
// immediately; persistent state = ah (32) + kss (8). Peak ~90 regs incl. load prefetch —
// fits (512,4)'s 128-reg cap without spill. Out projection retires per ct (oacc = 8 regs).
__global__ __launch_bounds__(512, 4) void k2_out(const float* __restrict__ x,
                                                 const unsigned short* __restrict__ wsWT,
                                                 const float* __restrict__ kvs_ws,
                                                 const float* __restrict__ kssum_ws,
                                                 const float* __restrict__ bout,
                                                 float* __restrict__ out) {
    __shared__ unsigned short lds[40960];       // 80 KB
    unsigned short* kvsT   = lds;               // [h*16+d][32 mpad] strip layout (8 KB)
    unsigned short* strips = lds + 4096;        // 8 waves x 512 shorts (8 KB)
    unsigned short* tile   = lds + 8192;        // 8 waves x (32 rows x 128 c) bf16 (64 KB)
    int t = threadIdx.x, w = t >> 6, lane = t & 63, q = lane >> 4, n15 = lane & 15;
    int b = blockIdx.x >> 2, seg = blockIdx.x & 3, rowbase = seg * 256;
    const unsigned short* wqT = wsWT;           // W_q frags
    const unsigned short* wvT = wsWT + 32768;   // W_v frags
    const unsigned short* woT = wsWT + 49152;   // W_out frags

    {   // build kvsT (bf16, transposed [h][d][m], m>=16 zero-padded)
        int row = t >> 2, part = t & 3, h = row >> 4, d = row & 15;
        unsigned es[8];
#pragma unroll
        for (int j = 0; j < 8; j += 2) {
            int m0 = part * 8 + j;
            unsigned lo = (m0     < 16) ? f2bf(kvs_ws[b * 2048 + h * 256 + m0 * 16 + d])      : 0;
            unsigned hi = (m0 + 1 < 16) ? f2bf(kvs_ws[b * 2048 + h * 256 + (m0 + 1) * 16 + d]) : 0;
            es[j] = lo | (hi << 16);
        }
        uint4 v = {es[0], es[2], es[4], es[6]};
        *reinterpret_cast<uint4*>(kvsT + row * 32 + ((part ^ (row & 3)) << 3)) = v;
    }

    float kss[8];
#pragma unroll
    for (int h = 0; h < 8; ++h) kss[h] = kssum_ws[b * 128 + h * 16 + n15];

    bf16x8 ah[2][4];
#pragma unroll
    for (int rs = 0; rs < 2; ++rs) {
        int row = rowbase + w * 32 + rs * 16 + n15;
        const float* xr = x + (size_t)(b * SEQ + row) * DIM;
#pragma unroll
        for (int ks = 0; ks < 4; ++ks) {
            float4 p0 = *reinterpret_cast<const float4*>(xr + ks * 32 + q * 8);
            float4 p1 = *reinterpret_cast<const float4*>(xr + ks * 32 + q * 8 + 4);
            ah[rs][ks] = cvt8(p0, p1);
        }
    }

    unsigned short* myS = strips + w * 512;     // per-wave 16x32 transpose strip
    unsigned short* tw  = tile + w * 4096;      // per-wave tile (32 rows x 128 c)
    {   // zero qs-strip pad (els 16..31 of each of 16 rows) — K=32 MFMA zero padding
        uint2 z = {0, 0};
        *reinterpret_cast<uint2*>(myS + strip_addr(n15, 16 + q * 4)) = z;
    }
    __syncthreads();                            // kvsT ready

    // ---- per-(rs,h): Q,V head-GEMMs -> fold norms -> numerator MFMA -> retire into tile ----
#pragma unroll
    for (int rs = 0; rs < 2; ++rs)
#pragma unroll
        for (int h = 0; h < 8; ++h) {
            f32x4 qa = (f32x4){0,0,0,0};
            f32x4 va = (f32x4){0,0,0,0};
#pragma unroll
            for (int ks = 0; ks < 4; ++ks) {
                bf16x8 qb = gfrag(wqT, h, ks, lane);
                bf16x8 vb = gfrag(wvT, h, ks, lane);
                qa = __builtin_amdgcn_mfma_f32_16x16x32_bf16(ah[rs][ks], qb, qa, 0, 0, 0);
                va = __builtin_amdgcn_mfma_f32_16x16x32_bf16(ah[rs][ks], vb, va, 0, 0, 0);
            }
            float pv[4];
#pragma unroll
            for (int r = 0; r < 4; ++r) {
                float val = qa[r];
                float ssq = r16sum(val * val);
                float tt  = r16sum(val * kss[h]);
                float di  = 1.0f / fmaxf(sqrtf(ssq), EPS);
                float inv = 1.0f / (tt * di + (float)SEQ);
                pv[r] = val * di * inv;                 // qs * inv
                va[r] *= (float)SEQ * inv;              // N * v * inv
            }
#pragma unroll
            for (int r = 0; r < 4; ++r)
                myS[strip_addr(q * 4 + r, n15)] = f2bf(pv[r]);
            bf16x8 aq = *reinterpret_cast<const bf16x8*>(myS + strip_addr(n15, q * 8));
            bf16x8 bk = *reinterpret_cast<const bf16x8*>(kvsT + strip_addr(h * 16 + n15, q * 8));
            va = __builtin_amdgcn_mfma_f32_16x16x32_bf16(aq, bk, va, 0, 0, 0);   // = pre
#pragma unroll
            for (int r = 0; r < 4; ++r) {
                int rt = rs * 16 + q * 4 + r;
                int colg = h * 2 + (n15 >> 3);
                tw[rt * 128 + (((colg ^ (rt & 15)) << 3) | (n15 & 7))] = f2bf(va[r]);
            }
        }

    // ---- out projection (tile is wave-private: no barrier), retire per ct ----
    bf16x8 ap[2][4];
#pragma unroll
    for (int rs = 0; rs < 2; ++rs)
#pragma unroll
        for (int ks = 0; ks < 4; ++ks) {
            int rt = rs * 16 + n15;
            ap[rs][ks] = *reinterpret_cast<const bf16x8*>(
                tw + rt * 128 + ((((ks << 2) + q) ^ (rt & 15)) << 3));
        }
#pragma unroll
    for (int ct = 0; ct < 8; ++ct) {
        f32x4 o0 = (f32x4){0,0,0,0};
        f32x4 o1 = (f32x4){0,0,0,0};
#pragma unroll
        for (int ks = 0; ks < 4; ++ks) {
            bf16x8 bb = gfrag(woT, ct, ks, lane);
            o0 = __builtin_amdgcn_mfma_f32_16x16x32_bf16(ap[0][ks], bb, o0, 0, 0, 0);
            o1 = __builtin_amdgcn_mfma_f32_16x16x32_bf16(ap[1][ks], bb, o1, 0, 0, 0);
        }
        float bo = bout[ct * 16 + n15];
#pragma unroll
        for (int r = 0; r < 4; ++r) {
            int row0 = rowbase + w * 32 + q * 4 + r;
            out[(size_t)(b * SEQ + row0) * DIM + ct * 16 + n15]      = o0[r] + bo;
            out[(size_t)(b * SEQ + row0 + 16) * DIM + ct * 16 + n15] = o1[r] + bo;
        }
    }
}

extern "C" void kernel_launch(void* const* d_in, const int* in_sizes, int n_in,
                              void* d_out, int out_size, void* d_ws, size_t ws_size,
                              hipStream_t stream) {
    const float* x    = (const float*)d_in[0];
    const float* Wqkv = (const float*)d_in[1];
    const float* Wout = (const float*)d_in[2];
    const float* bout = (const float*)d_in[3];
    float* out = (float*)d_out;

    float* kvs_ws   = (float*)d_ws;
    float* kssum_ws = kvs_ws + KVS_F;
    unsigned short* wsWT = (unsigned short*)((char*)d_ws + (size_t)ZERO_F * 4);

    hipMemsetAsync(d_ws, 0, (size_t)ZERO_F * 4, stream);   // zero kvs + kssum (graph-capturable)
    k0_prep<<<dim3(256), dim3(256), 0, stream>>>(Wqkv, Wout, wsWT);
    k1_kv<<<dim3(768), dim3(512), 0, stream>>>(x, wsWT, kvs_ws, kssum_ws);
    k2_out<<<dim3(768), dim3(512), 0, stream>>>(x, wsWT, kvs_ws, kssum_ws, bout, out);
}

// Round 4
// 282.218 us; speedup vs baseline: 1.2784x; 1.1230x over previous
//
#include <hip/hip_runtime.h>

// AttentionLayer, MFMA bf16 version.
// x (192,1024,128) f32; W_qkv (128,384) f32; W_out (128,128) f32; b_out (128) f32.
// out (192,1024,128) f32. H=8 heads x hd=16, N=SEQ=1024.
#define NBATCH 192
#define SEQ    1024
#define DIM    128
#define NH     8
#define EPS    1e-12f

typedef short bf16x8 __attribute__((ext_vector_type(8)));
typedef float f32x4  __attribute__((ext_vector_type(4)));

// ws layout: kvs 393216 f32, kssum 24576 f32, then bf16 wsWT frag-major [4][2048 frags][8]
#define KVS_F  393216
#define ZERO_F 417792

static __device__ __forceinline__ unsigned short f2bf(float f) {
    unsigned u = __builtin_bit_cast(unsigned, f);
    u += 0x7fff + ((u >> 16) & 1);          // RTNE
    return (unsigned short)(u >> 16);
}

template <int CTRL>
static __device__ __forceinline__ float dpp_add(float v) {
    int j = __builtin_amdgcn_mov_dpp(__builtin_bit_cast(int, v), CTRL, 0xf, 0xf, false);
    return v + __builtin_bit_cast(float, j);
}
// sum over the 16 lanes of a DPP row (= over n15); all lanes get the result
static __device__ __forceinline__ float r16sum(float v) {
    v = dpp_add<0xB1>(v);    // quad_perm [1,0,3,2]  : xor1
    v = dpp_add<0x4E>(v);    // quad_perm [2,3,0,1]  : xor2
    v = dpp_add<0x141>(v);   // row_half_mirror      : pairs 4-groups
    v = dpp_add<0x140>(v);   // row_mirror           : pairs 8-groups
    return v;
}

// strip: [row][32 els], granule(8 el)-swizzled by row&3. addr in shorts.
static __device__ __forceinline__ int strip_addr(int row, int el) {
    return row * 32 + ((((el >> 3) ^ (row & 3)) << 3) | (el & 7));
}

static __device__ __forceinline__ uint2 pack4(float a, float b, float c, float d) {
    uint2 r;
    r.x = (unsigned)f2bf(a) | ((unsigned)f2bf(b) << 16);
    r.y = (unsigned)f2bf(c) | ((unsigned)f2bf(d) << 16);
    return r;
}

static __device__ __forceinline__ bf16x8 cvt8(float4 a, float4 b) {
    bf16x8 r;
    r[0] = (short)f2bf(a.x); r[1] = (short)f2bf(a.y); r[2] = (short)f2bf(a.z); r[3] = (short)f2bf(a.w);
    r[4] = (short)f2bf(b.x); r[5] = (short)f2bf(b.y); r[6] = (short)f2bf(b.z); r[7] = (short)f2bf(b.w);
    return r;
}

// B-frag direct from global, frag-major wsWT: frag id = ((ct*4+ks)*4+q)*16+n15,
// 8 consecutive shorts per lane -> wave reads 1 KB contiguous (L1/L2 resident).
static __device__ __forceinline__ bf16x8 gfrag(const unsigned short* __restrict__ wT,
                                               int ct, int ks, int lane) {
    return *reinterpret_cast<const bf16x8*>(wT + ((ct * 4 + ks) * 64 + lane) * 8);
}

// ---------------- k0: convert weights into frag-major bf16 ----------------
// wsWT[which][(((ct*4+ks)*4+q)*16+n15)*8 + j] = W[k=ks*32+q*8+j][n=ct*16+n15]
__global__ __launch_bounds__(256) void k0_prep(const float* __restrict__ Wqkv,
                                               const float* __restrict__ Wout,
                                               unsigned short* __restrict__ wsWT) {
    int i = blockIdx.x * 256 + threadIdx.x;     // 0..65535, writes coalesced
    int which = i >> 14, e = i & 16383;
    int j = e & 7, f = e >> 3;
    int n15 = f & 15, q = (f >> 4) & 3, ks = (f >> 6) & 3, ct = f >> 8;
    int k = ks * 32 + q * 8 + j, n = ct * 16 + n15;
    float v = (which < 3) ? Wqkv[k * 384 + which * 128 + n] : Wout[k * 128 + n];
    wsWT[i] = f2bf(v);
}

// ---------------- k1: k,v GEMM -> normalize k -> kvs & ks_sum ----------------
// LDS 80 KB (2 blocks/CU): redf 64K (block kvs reduction) + strips 16K (per-wave).
// DYNAMIC ct loop (unroll 1): stops cross-iteration gfrag hoisting -> no spills.
// All per-ct state is iteration-local (ksum scalar, kacc f32x4 retired to LDS).
__global__ __launch_bounds__(512, 4) void k1_kv(const float* __restrict__ x,
                                                const unsigned short* __restrict__ wsWT,
                                                float* __restrict__ kvs_ws,
                                                float* __restrict__ kssum_ws) {
    __shared__ float redf[16384];               // 64 KB
    __shared__ unsigned short strips[8192];     // 16 KB
    int t = threadIdx.x, w = t >> 6, lane = t & 63, q = lane >> 4, n15 = lane & 15;
    int b = blockIdx.x >> 2, seg = blockIdx.x & 3;
    const unsigned short* wkT = wsWT + 16384;   // W_k frags
    const unsigned short* wvT = wsWT + 32768;   // W_v frags
    unsigned short* knS = strips + w * 1024;    // [16 m][32 l]
    unsigned short* vS  = knS + 512;            // [16 d][32 l]

    bf16x8 ah[2][4];
#pragma unroll
    for (int rs = 0; rs < 2; ++rs) {
        int row = seg * 256 + w * 32 + rs * 16 + n15;
        const float* xr = x + (size_t)(b * SEQ + row) * DIM;
#pragma unroll
        for (int ks = 0; ks < 4; ++ks) {
            float4 p0 = *reinterpret_cast<const float4*>(xr + ks * 32 + q * 8);
            float4 p1 = *reinterpret_cast<const float4*>(xr + ks * 32 + q * 8 + 4);
            ah[rs][ks] = cvt8(p0, p1);
        }
    }

#pragma unroll 1
    for (int ct = 0; ct < 8; ++ct) {
        f32x4 ka[2] = {(f32x4){0,0,0,0}, (f32x4){0,0,0,0}};
        f32x4 va[2] = {(f32x4){0,0,0,0}, (f32x4){0,0,0,0}};
#pragma unroll
        for (int ks = 0; ks < 4; ++ks) {
            bf16x8 kb = gfrag(wkT, ct, ks, lane);
            bf16x8 vb = gfrag(wvT, ct, ks, lane);
#pragma unroll
            for (int rs = 0; rs < 2; ++rs) {
                ka[rs] = __builtin_amdgcn_mfma_f32_16x16x32_bf16(ah[rs][ks], kb, ka[rs], 0, 0, 0);
                va[rs] = __builtin_amdgcn_mfma_f32_16x16x32_bf16(ah[rs][ks], vb, va[rs], 0, 0, 0);
            }
        }
        float ksum = 0.f;
        // normalize k rows (reduce over n15 = head dim), stash kn & v into strips
#pragma unroll
        for (int rs = 0; rs < 2; ++rs) {
            float kn[4];
#pragma unroll
            for (int r = 0; r < 4; ++r) {
                float val = ka[rs][r];
                float ssq = r16sum(val * val);
                float di  = 1.0f / fmaxf(sqrtf(ssq), EPS);
                kn[r] = val * di;
                ksum += kn[r];
            }
            *reinterpret_cast<uint2*>(knS + strip_addr(n15, rs * 16 + q * 4)) =
                pack4(kn[0], kn[1], kn[2], kn[3]);
            *reinterpret_cast<uint2*>(vS + strip_addr(n15, rs * 16 + q * 4)) =
                pack4(va[rs][0], va[rs][1], va[rs][2], va[rs][3]);
        }
        // kvs[h][m][d] = kn^T (m x l=32) . v (l x d)  — one K=32 MFMA, retire to LDS
        bf16x8 aK = *reinterpret_cast<const bf16x8*>(knS + strip_addr(n15, q * 8));
        bf16x8 bV = *reinterpret_cast<const bf16x8*>(vS + strip_addr(n15, q * 8));
        f32x4 kacc = __builtin_amdgcn_mfma_f32_16x16x32_bf16(aK, bV, (f32x4){0,0,0,0}, 0, 0, 0);
#pragma unroll
        for (int r = 0; r < 4; ++r)
            redf[w * 2048 + ct * 256 + (q * 4 + r) * 16 + n15] = kacc[r];
        // ks_sum: reduce over q-groups (rows), then atomics from lanes 0..15
        float s = ksum;
        s += __shfl_xor(s, 16); s += __shfl_xor(s, 32);
        if (lane < 16) atomicAdd(&kssum_ws[b * 128 + ct * 16 + n15], s);
    }

    // block-level kvs reduction over 8 waves, then one atomic per element
    __syncthreads();
#pragma unroll
    for (int i = 0; i < 4; ++i) {
        int el = i * 512 + t;
        float s = 0.f;
#pragma unroll
        for (int ww = 0; ww < 8; ++ww) s += redf[ww * 2048 + el];
        atomicAdd(&kvs_ws[b * 2048 + el], s);
    }
}

// ---------------- k2: per-(rs,h) {Q,V head-GEMM -> fold -> num MFMA -> tile} -> out proj ----------------
// LDS 80 KB (2 blocks/CU): kvsT 8K | strips 8K | per-wave tile 64K. ONE __syncthreads (kvsT).
// DYNAMIC h and ct loops (unroll 1): stops cross-iteration gfrag hoisting -> no spills.
// kss reloaded from global per (rs,h) iteration (L1-hit) to avoid a runtime-indexed array.
__global__ __launch_bounds__(512, 4) void k2_out(const float* __restrict__ x,
                                                 const unsigned short* __restrict__ wsWT,
                                                 const float* __restrict__ kvs_ws,
                                                 const float* __restrict__ kssum_ws,
                                                 const float* __restrict__ bout,
                                                 float* __restrict__ out) {
    __shared__ unsigned short lds[40960];       // 80 KB
    unsigned short* kvsT   = lds;               // [h*16+d][32 mpad] strip layout (8 KB)
    unsigned short* strips = lds + 4096;        // 8 waves x 512 shorts (8 KB)
    unsigned short* tile   = lds + 8192;        // 8 waves x (32 rows x 128 c) bf16 (64 KB)
    int t = threadIdx.x, w = t >> 6, lane = t & 63, q = lane >> 4, n15 = lane & 15;
    int b = blockIdx.x >> 2, seg = blockIdx.x & 3, rowbase = seg * 256;
    const unsigned short* wqT = wsWT;           // W_q frags
    const unsigned short* wvT = wsWT + 32768;   // W_v frags
    const unsigned short* woT = wsWT + 49152;   // W_out frags

    {   // build kvsT (bf16, transposed [h][d][m], m>=16 zero-padded)
        int row = t >> 2, part = t & 3, h = row >> 4, d = row & 15;
        unsigned es[8];
#pragma unroll
        for (int j = 0; j < 8; j += 2) {
            int m0 = part * 8 + j;
            unsigned lo = (m0     < 16) ? f2bf(kvs_ws[b * 2048 + h * 256 + m0 * 16 + d])      : 0;
            unsigned hi = (m0 + 1 < 16) ? f2bf(kvs_ws[b * 2048 + h * 256 + (m0 + 1) * 16 + d]) : 0;
            es[j] = lo | (hi << 16);
        }
        uint4 v = {es[0], es[2], es[4], es[6]};
        *reinterpret_cast<uint4*>(kvsT + row * 32 + ((part ^ (row & 3)) << 3)) = v;
    }

    bf16x8 ah[2][4];
#pragma unroll
    for (int rs = 0; rs < 2; ++rs) {
        int row = rowbase + w * 32 + rs * 16 + n15;
        const float* xr = x + (size_t)(b * SEQ + row) * DIM;
#pragma unroll
        for (int ks = 0; ks < 4; ++ks) {
            float4 p0 = *reinterpret_cast<const float4*>(xr + ks * 32 + q * 8);
            float4 p1 = *reinterpret_cast<const float4*>(xr + ks * 32 + q * 8 + 4);
            ah[rs][ks] = cvt8(p0, p1);
        }
    }

    unsigned short* myS = strips + w * 512;     // per-wave 16x32 transpose strip
    unsigned short* tw  = tile + w * 4096;      // per-wave tile (32 rows x 128 c)
    {   // zero qs-strip pad (els 16..31 of each of 16 rows) — K=32 MFMA zero padding
        uint2 z = {0, 0};
        *reinterpret_cast<uint2*>(myS + strip_addr(n15, 16 + q * 4)) = z;
    }
    __syncthreads();                            // kvsT ready

    // ---- per-(rs,h): Q,V head-GEMMs -> fold norms -> numerator MFMA -> retire into tile ----
#pragma unroll
    for (int rs = 0; rs < 2; ++rs)
#pragma unroll 1
        for (int h = 0; h < 8; ++h) {
            float kssh = kssum_ws[b * 128 + h * 16 + n15];   // L1-hit reload, no reg array
            f32x4 qa = (f32x4){0,0,0,0};
            f32x4 va = (f32x4){0,0,0,0};
#pragma unroll
            for (int ks = 0; ks < 4; ++ks) {
                bf16x8 qb = gfrag(wqT, h, ks, lane);
                bf16x8 vb = gfrag(wvT, h, ks, lane);
                qa = __builtin_amdgcn_mfma_f32_16x16x32_bf16(ah[rs][ks], qb, qa, 0, 0, 0);
                va = __builtin_amdgcn_mfma_f32_16x16x32_bf16(ah[rs][ks], vb, va, 0, 0, 0);
            }
            float pv[4];
#pragma unroll
            for (int r = 0; r < 4; ++r) {
                float val = qa[r];
                float ssq = r16sum(val * val);
                float tt  = r16sum(val * kssh);
                float di  = 1.0f / fmaxf(sqrtf(ssq), EPS);
                float inv = 1.0f / (tt * di + (float)SEQ);
                pv[r] = val * di * inv;                 // qs * inv
                va[r] *= (float)SEQ * inv;              // N * v * inv
            }
#pragma unroll
            for (int r = 0; r < 4; ++r)
                myS[strip_addr(q * 4 + r, n15)] = f2bf(pv[r]);
            bf16x8 aq = *reinterpret_cast<const bf16x8*>(myS + strip_addr(n15, q * 8));
            bf16x8 bk = *reinterpret_cast<const bf16x8*>(kvsT + strip_addr(h * 16 + n15, q * 8));
            va = __builtin_amdgcn_mfma_f32_16x16x32_bf16(aq, bk, va, 0, 0, 0);   // = pre
#pragma unroll
            for (int r = 0; r < 4; ++r) {
                int rt = rs * 16 + q * 4 + r;
                int colg = h * 2 + (n15 >> 3);
                tw[rt * 128 + (((colg ^ (rt & 15)) << 3) | (n15 & 7))] = f2bf(va[r]);
            }
        }

    // ---- out projection (tile is wave-private: no barrier), retire per ct ----
    bf16x8 ap[2][4];
#pragma unroll
    for (int rs = 0; rs < 2; ++rs)
#pragma unroll
        for (int ks = 0; ks < 4; ++ks) {
            int rt = rs * 16 + n15;
            ap[rs][ks] = *reinterpret_cast<const bf16x8*>(
                tw + rt * 128 + ((((ks << 2) + q) ^ (rt & 15)) << 3));
        }
#pragma unroll 1
    for (int ct = 0; ct < 8; ++ct) {
        f32x4 o0 = (f32x4){0,0,0,0};
        f32x4 o1 = (f32x4){0,0,0,0};
#pragma unroll
        for (int ks = 0; ks < 4; ++ks) {
            bf16x8 bb = gfrag(woT, ct, ks, lane);
            o0 = __builtin_amdgcn_mfma_f32_16x16x32_bf16(ap[0][ks], bb, o0, 0, 0, 0);
            o1 = __builtin_amdgcn_mfma_f32_16x16x32_bf16(ap[1][ks], bb, o1, 0, 0, 0);
        }
        float bo = bout[ct * 16 + n15];
#pragma unroll
        for (int r = 0; r < 4; ++r) {
            int row0 = rowbase + w * 32 + q * 4 + r;
            out[(size_t)(b * SEQ + row0) * DIM + ct * 16 + n15]      = o0[r] + bo;
            out[(size_t)(b * SEQ + row0 + 16) * DIM + ct * 16 + n15] = o1[r] + bo;
        }
    }
}

extern "C" void kernel_launch(void* const* d_in, const int* in_sizes, int n_in,
                              void* d_out, int out_size, void* d_ws, size_t ws_size,
                              hipStream_t stream) {
    const float* x    = (const float*)d_in[0];
    const float* Wqkv = (const float*)d_in[1];
    const float* Wout = (const float*)d_in[2];
    const float* bout = (const float*)d_in[3];
    float* out = (float*)d_out;

    float* kvs_ws   = (float*)d_ws;
    float* kssum_ws = kvs_ws + KVS_F;
    unsigned short* wsWT = (unsigned short*)((char*)d_ws + (size_t)ZERO_F * 4);

    hipMemsetAsync(d_ws, 0, (size_t)ZERO_F * 4, stream);   // zero kvs + kssum (graph-capturable)
    k0_prep<<<dim3(256), dim3(256), 0, stream>>>(Wqkv, Wout, wsWT);
    k1_kv<<<dim3(768), dim3(512), 0, stream>>>(x, wsWT, kvs_ws, kssum_ws);
    k2_out<<<dim3(768), dim3(512), 0, stream>>>(x, wsWT, kvs_ws, kssum_ws, bout, out);
}